// Round 1
// baseline (191.471 us; speedup 1.0000x reference)
//
#include <hip/hip_runtime.h>

#define B_ 64
#define S_ 200
#define H_ 256
#define A_ 16
#define M_ (B_*S_)
#define NEGV (-1000000000.0f)

// ---------------- Phase A ----------------
// Per 16-row tile: tma_in@Wa1 -> leaky -> w = h.Wa2+ba2 (pad-masked);
// tanh(item@W_lin+b_lin)+item -> LN -> moe; gates = item@asp^T -> argmax idx.
#define TSA 16
#define WLSTR 264
#define XLSTR 20

__global__ __launch_bounds__(256) void phaseA_kernel(
    const float* __restrict__ item, const int* __restrict__ iseq,
    const int* __restrict__ tseq, const float* __restrict__ W_lin,
    const float* __restrict__ b_lin, const float* __restrict__ asp,
    const float* __restrict__ pos, const float* __restrict__ tdt,
    const float* __restrict__ tdn, const float* __restrict__ Wa1,
    const float* __restrict__ ba1, const float* __restrict__ Wa2,
    const float* __restrict__ ba2, const float* __restrict__ g_ln,
    const float* __restrict__ b_ln,
    float* __restrict__ gates_raw,   // OUT1 region (raw now, softmaxed by phaseC)
    float* __restrict__ moe_out,     // OUT3 region (scratch; overwritten by gather)
    float* __restrict__ idxf,        // OUT5 region (idx as float)
    float* __restrict__ w_out)       // ws
{
  __shared__ float Wl[16*WLSTR];
  __shared__ float Xl[TSA*XLSTR];
  __shared__ float gL[TSA*XLSTR];
  __shared__ int   sL[TSA], ttL[TSA], tnL[TSA], padL[TSA];
  __shared__ float redA[TSA], redB[TSA];

  const int t  = threadIdx.x;
  const int m0 = blockIdx.x * TSA;
  const int tn = t & 31;
  const int tm = t >> 5;

  if (t < TSA) {
    int m = m0 + t;
    sL[t]  = m % S_;
    ttL[t] = tseq[2*m];
    tnL[t] = tseq[2*m+1];
    padL[t] = (iseq[m] == 0) ? 1 : 0;
  }
  __syncthreads();

  float acc[2][8];
  float mvals[2][8];

  for (int gemm = 0; gemm < 2; ++gemm) {
    #pragma unroll
    for (int i = 0; i < 2; ++i)
      #pragma unroll
      for (int j = 0; j < 8; ++j) acc[i][j] = 0.f;

    const float* __restrict__ Wsrc = (gemm == 0) ? Wa1 : W_lin;

    for (int k0 = 0; k0 < H_; k0 += 16) {
      __syncthreads();
      // stage W tile (16 x 256)
      #pragma unroll
      for (int it = 0; it < 4; ++it) {
        int f = t + 256*it;
        int kr = f >> 6, c = f & 63;
        *(float4*)&Wl[kr*WLSTR + 4*c] = *(const float4*)&Wsrc[(k0+kr)*H_ + 4*c];
      }
      // stage X tile (16 x 16)
      if (t < 64) {
        int r = t >> 2, q = t & 3;
        int m = m0 + r;
        float4 xv = *(const float4*)&item[m*H_ + k0 + 4*q];
        if (gemm == 0) {
          float4 xp = *(const float4*)&pos[sL[r]*H_ + k0 + 4*q];
          float4 xt = *(const float4*)&tdt[ttL[r]*H_ + k0 + 4*q];
          float4 xn = *(const float4*)&tdn[tnL[r]*H_ + k0 + 4*q];
          xv.x += xp.x + xt.x + xn.x; xv.y += xp.y + xt.y + xn.y;
          xv.z += xp.z + xt.z + xn.z; xv.w += xp.w + xt.w + xn.w;
        }
        *(float4*)&Xl[r*XLSTR + 4*q] = xv;
      }
      __syncthreads();
      // compute
      #pragma unroll
      for (int kk = 0; kk < 16; kk += 4) {
        float4 x0 = *(const float4*)&Xl[(2*tm+0)*XLSTR + kk];
        float4 x1 = *(const float4*)&Xl[(2*tm+1)*XLSTR + kk];
        float xs0[4] = {x0.x, x0.y, x0.z, x0.w};
        float xs1[4] = {x1.x, x1.y, x1.z, x1.w};
        #pragma unroll
        for (int d = 0; d < 4; ++d) {
          float4 wa = *(const float4*)&Wl[(kk+d)*WLSTR + 4*tn];
          float4 wb = *(const float4*)&Wl[(kk+d)*WLSTR + 128 + 4*tn];
          float a0 = xs0[d], a1 = xs1[d];
          acc[0][0] += a0*wa.x; acc[0][1] += a0*wa.y; acc[0][2] += a0*wa.z; acc[0][3] += a0*wa.w;
          acc[0][4] += a0*wb.x; acc[0][5] += a0*wb.y; acc[0][6] += a0*wb.z; acc[0][7] += a0*wb.w;
          acc[1][0] += a1*wa.x; acc[1][1] += a1*wa.y; acc[1][2] += a1*wa.z; acc[1][3] += a1*wa.w;
          acc[1][4] += a1*wb.x; acc[1][5] += a1*wb.y; acc[1][6] += a1*wb.z; acc[1][7] += a1*wb.w;
        }
      }
    }
    __syncthreads();

    if (gemm == 0) {
      // h = leaky(acc+ba1); w = h.Wa2 + ba2 (pad -> NEG)
      float4 bv0 = *(const float4*)&ba1[4*tn];
      float4 bv1 = *(const float4*)&ba1[128 + 4*tn];
      float4 w20 = *(const float4*)&Wa2[4*tn];
      float4 w21 = *(const float4*)&Wa2[128 + 4*tn];
      float bas[8] = {bv0.x,bv0.y,bv0.z,bv0.w,bv1.x,bv1.y,bv1.z,bv1.w};
      float w2s[8] = {w20.x,w20.y,w20.z,w20.w,w21.x,w21.y,w21.z,w21.w};
      float bb2 = ba2[0];
      #pragma unroll
      for (int i = 0; i < 2; ++i) {
        float wp = 0.f;
        #pragma unroll
        for (int j = 0; j < 8; ++j) {
          float hh = acc[i][j] + bas[j];
          hh = (hh >= 0.f) ? hh : 0.01f*hh;
          wp += hh * w2s[j];
        }
        #pragma unroll
        for (int mk = 16; mk; mk >>= 1) wp += __shfl_xor(wp, mk);
        if (tn == 0) {
          int r = 2*tm + i;
          w_out[m0 + r] = padL[r] ? NEGV : (wp + bb2);
        }
      }
    } else {
      // moe = LN(tanh(acc+b_lin) + item)
      float4 bl0 = *(const float4*)&b_lin[4*tn];
      float4 bl1 = *(const float4*)&b_lin[128 + 4*tn];
      float bls[8] = {bl0.x,bl0.y,bl0.z,bl0.w,bl1.x,bl1.y,bl1.z,bl1.w};
      float s1[2], s2[2];
      #pragma unroll
      for (int i = 0; i < 2; ++i) {
        int m = m0 + 2*tm + i;
        float4 it0 = *(const float4*)&item[m*H_ + 4*tn];
        float4 it1 = *(const float4*)&item[m*H_ + 128 + 4*tn];
        float itv[8] = {it0.x,it0.y,it0.z,it0.w,it1.x,it1.y,it1.z,it1.w};
        s1[i] = 0.f; s2[i] = 0.f;
        #pragma unroll
        for (int j = 0; j < 8; ++j) {
          float v = tanhf(acc[i][j] + bls[j]) + itv[j];
          mvals[i][j] = v; s1[i] += v; s2[i] += v*v;
        }
        #pragma unroll
        for (int mk = 16; mk; mk >>= 1) {
          s1[i] += __shfl_xor(s1[i], mk);
          s2[i] += __shfl_xor(s2[i], mk);
        }
        if (tn == 0) { redA[2*tm+i] = s1[i]; redB[2*tm+i] = s2[i]; }
      }
      __syncthreads();
      float4 gg0 = *(const float4*)&g_ln[4*tn];
      float4 gg1 = *(const float4*)&g_ln[128 + 4*tn];
      float4 bb0 = *(const float4*)&b_ln[4*tn];
      float4 bb1 = *(const float4*)&b_ln[128 + 4*tn];
      float gs[8]  = {gg0.x,gg0.y,gg0.z,gg0.w,gg1.x,gg1.y,gg1.z,gg1.w};
      float bs2[8] = {bb0.x,bb0.y,bb0.z,bb0.w,bb1.x,bb1.y,bb1.z,bb1.w};
      #pragma unroll
      for (int i = 0; i < 2; ++i) {
        int r = 2*tm + i; int m = m0 + r;
        float mu  = redA[r] * (1.0f/H_);
        float var = redB[r] * (1.0f/H_) - mu*mu;
        float rs  = 1.0f / sqrtf(fmaxf(var, 0.f) + 1e-12f);
        float o[8];
        #pragma unroll
        for (int j = 0; j < 8; ++j) o[j] = (mvals[i][j] - mu)*rs*gs[j] + bs2[j];
        float4 o0; o0.x=o[0]; o0.y=o[1]; o0.z=o[2]; o0.w=o[3];
        float4 o1; o1.x=o[4]; o1.y=o[5]; o1.z=o[6]; o1.w=o[7];
        *(float4*)&moe_out[m*H_ + 4*tn] = o0;
        *(float4*)&moe_out[m*H_ + 128 + 4*tn] = o1;
      }
    }
  }

  // ---- gates = item @ asp^T ----
  __syncthreads();
  #pragma unroll
  for (int it = 0; it < 4; ++it) {
    int f = t + 256*it;
    int kr = f >> 6, c = f & 63;
    *(float4*)&Wl[kr*WLSTR + 4*c] = *(const float4*)&asp[kr*H_ + 4*c];
  }
  __syncthreads();
  {
    int r = t >> 4, a = t & 15;
    int m = m0 + r;
    float g = 0.f;
    #pragma unroll 4
    for (int k4 = 0; k4 < 64; ++k4) {
      float4 xv = *(const float4*)&item[m*H_ + 4*k4];
      float4 av = *(const float4*)&Wl[a*WLSTR + 4*k4];
      g += xv.x*av.x + xv.y*av.y + xv.z*av.z + xv.w*av.w;
    }
    gL[r*XLSTR + a] = g;
  }
  __syncthreads();
  if (t < 64) {
    int r = t >> 2, q = t & 3;
    float4 gv;
    gv.x = gL[r*XLSTR + 4*q + 0]; gv.y = gL[r*XLSTR + 4*q + 1];
    gv.z = gL[r*XLSTR + 4*q + 2]; gv.w = gL[r*XLSTR + 4*q + 3];
    *(float4*)&gates_raw[(m0+r)*A_ + 4*q] = gv;
  }
  if (t < TSA) {
    int r = t;
    float best = gL[r*XLSTR]; int bi = 0;
    #pragma unroll
    for (int a = 1; a < 16; ++a) {
      float v = gL[r*XLSTR + a];
      if (v > best) { best = v; bi = a; }
    }
    idxf[m0 + r] = (float)bi;
  }
}

// ---------------- Phase C (one block per batch) ----------------
__device__ __forceinline__ float blk_max(float v, float* red) {
  #pragma unroll
  for (int mk = 32; mk; mk >>= 1) v = fmaxf(v, __shfl_xor(v, mk));
  int t = threadIdx.x;
  if ((t & 63) == 0) red[t >> 6] = v;
  __syncthreads();
  if (t < 64) {
    float x = (t < 16) ? red[t] : -3.0e38f;
    #pragma unroll
    for (int mk = 8; mk; mk >>= 1) x = fmaxf(x, __shfl_xor(x, mk));
    if (t == 0) red[0] = x;
  }
  __syncthreads();
  float r = red[0];
  __syncthreads();
  return r;
}

__device__ __forceinline__ float blk_sum(float v, float* red) {
  #pragma unroll
  for (int mk = 32; mk; mk >>= 1) v += __shfl_xor(v, mk);
  int t = threadIdx.x;
  if ((t & 63) == 0) red[t >> 6] = v;
  __syncthreads();
  if (t < 64) {
    float x = (t < 16) ? red[t] : 0.f;
    #pragma unroll
    for (int mk = 8; mk; mk >>= 1) x += __shfl_xor(x, mk);
    if (t == 0) red[0] = x;
  }
  __syncthreads();
  float r = red[0];
  __syncthreads();
  return r;
}

__global__ __launch_bounds__(1024) void phaseC_kernel(
    const int* __restrict__ iseq, const float* __restrict__ w_in,
    const float* __restrict__ moe, const float* __restrict__ idxf,
    float* __restrict__ gates_rs,   // raw in -> softmax out (OUT1)
    float* __restrict__ cap_out,    // OUT0
    float* __restrict__ mask_out,   // OUT2
    float* __restrict__ aidx_out)   // OUT4
{
  __shared__ float bij[S_*20];
  __shared__ float wgt[S_*20];
  __shared__ float capl[A_*260];
  __shared__ float tmaL[S_];
  __shared__ float red[16];
  __shared__ float maskf[A_];
  __shared__ int counts[A_], maxpos[A_];
  __shared__ int idxl[S_];
  __shared__ int padl[S_];

  const int t = threadIdx.x;
  const int b = blockIdx.x;
  const int base = b * S_;

  if (t < A_) { counts[t] = 0; maxpos[t] = -1; }
  float wv = -3.0e38f;
  if (t < S_) {
    int s = t;
    padl[s] = (iseq[base+s] == 0) ? 1 : 0;
    idxl[s] = (int)idxf[base+s];
    wv = w_in[base+s];
    #pragma unroll
    for (int q = 0; q < 4; ++q)
      *(float4*)&bij[s*20 + 4*q] = *(const float4*)&gates_rs[(base+s)*A_ + 4*q];
  }
  __syncthreads();

  if (t < S_ && !padl[t]) {
    atomicAdd(&counts[idxl[t]], 1);
    atomicMax(&maxpos[idxl[t]], t + 1);
  }
  // gates softmax (unmasked) -> overwrite OUT1
  if (t < S_) {
    int s = t;
    float row[16]; float mx = -3.0e38f;
    #pragma unroll
    for (int a = 0; a < 16; ++a) { row[a] = bij[s*20+a]; mx = fmaxf(mx, row[a]); }
    float sm = 0.f;
    #pragma unroll
    for (int a = 0; a < 16; ++a) { row[a] = expf(row[a] - mx); sm += row[a]; }
    float inv = 1.f / sm;
    #pragma unroll
    for (int q = 0; q < 4; ++q) {
      float4 o; o.x=row[4*q]*inv; o.y=row[4*q+1]*inv; o.z=row[4*q+2]*inv; o.w=row[4*q+3]*inv;
      *(float4*)&gates_rs[(base+s)*A_ + 4*q] = o;
    }
  }
  // tma = softmax(w) over s (w already pad-masked with NEG)
  float mxw = blk_max(wv, red);
  float ev = (t < S_) ? expf(wv - mxw) : 0.f;
  float sw = blk_sum(ev, red);
  if (t < S_) tmaL[t] = ev / sw;
  __syncthreads();
  if (t < A_) {
    int c = counts[t];
    float mkv = (c == 0) ? 1.f : 0.f;
    maskf[t] = mkv;
    mask_out[b*A_ + t] = mkv;
    int mp = maxpos[t];
    aidx_out[b*A_ + t] = (mp > 0) ? (float)(mp - 1) : -1.f;
  }
  __syncthreads();

  for (int iter = 0; iter < 3; ++iter) {
    // step1: cij = softmax_a(mask? NEG : bij); wgt = (pad?0:cij)*tma
    if (t < S_) {
      int s = t;
      float row[16]; float mx = -3.0e38f;
      #pragma unroll
      for (int a = 0; a < 16; ++a) {
        float v = bij[s*20+a];
        v = (maskf[a] > 0.5f) ? NEGV : v;
        row[a] = v; mx = fmaxf(mx, v);
      }
      float sm = 0.f;
      #pragma unroll
      for (int a = 0; a < 16; ++a) { row[a] = expf(row[a] - mx); sm += row[a]; }
      float sc = (padl[s] ? 0.f : tmaL[s]) / sm;
      #pragma unroll
      for (int q = 0; q < 4; ++q) {
        float4 o; o.x=row[4*q]*sc; o.y=row[4*q+1]*sc; o.z=row[4*q+2]*sc; o.w=row[4*q+3]*sc;
        *(float4*)&wgt[s*20 + 4*q] = o;
      }
    }
    __syncthreads();
    // step2: cap[a][h] = sum_s wgt[s][a] * moe[s][h]
    {
      int h = t & 255, rep = t >> 8, a0 = rep << 2;
      float ac0=0.f, ac1=0.f, ac2=0.f, ac3=0.f;
      const float* mrow = &moe[(size_t)base*H_ + h];
      #pragma unroll 4
      for (int s = 0; s < S_; ++s) {
        float mv = mrow[s*H_];
        float4 wv4 = *(const float4*)&wgt[s*20 + a0];
        ac0 += wv4.x*mv; ac1 += wv4.y*mv; ac2 += wv4.z*mv; ac3 += wv4.w*mv;
      }
      capl[(a0+0)*260 + h] = ac0;
      capl[(a0+1)*260 + h] = ac1;
      capl[(a0+2)*260 + h] = ac2;
      capl[(a0+3)*260 + h] = ac3;
    }
    __syncthreads();
    // step3: squash per a (wave w handles a=w)
    {
      int w = t >> 6, l = t & 63;
      float v = 0.f;
      #pragma unroll
      for (int q = 0; q < 4; ++q) { float c = capl[w*260 + l + 64*q]; v += c*c; }
      #pragma unroll
      for (int mk = 32; mk; mk >>= 1) v += __shfl_xor(v, mk);
      float sc = v / (1.f + v) / sqrtf(v + 1e-9f);
      #pragma unroll
      for (int q = 0; q < 4; ++q) capl[w*260 + l + 64*q] *= sc;
    }
    __syncthreads();
    // step4: bij[s][a] += moe[s] . cap[a]   (dead on last iter -> skip)
    if (iter < 2) {
      int a = t & 15, srow = t >> 4;
      for (int so = 0; so < 4; ++so) {
        int s = so*64 + srow;
        if (s < S_) {
          const float* mp_ = &moe[(size_t)(base+s)*H_];
          float accd = 0.f;
          #pragma unroll 4
          for (int k4 = 0; k4 < 64; ++k4) {
            float4 mv = *(const float4*)&mp_[4*k4];
            float4 cv = *(const float4*)&capl[a*260 + 4*k4];
            accd += mv.x*cv.x + mv.y*cv.y + mv.z*cv.z + mv.w*cv.w;
          }
          bij[s*20 + a] += accd;
        }
      }
      __syncthreads();
    }
  }
  // write final cap
  #pragma unroll
  for (int q = 0; q < 4; ++q) {
    int e = t + 1024*q;
    int a = e >> 8, h = e & 255;
    cap_out[(b*A_ + a)*H_ + h] = capl[a*260 + h];
  }
}

// ---------------- gather: activated[b,s,:] = cap[b, idx[b,s], :] ----------------
__global__ __launch_bounds__(256) void gather_kernel(
    const float* __restrict__ capv, const float* __restrict__ idxf,
    float* __restrict__ act)
{
  int e4 = blockIdx.x * 256 + threadIdx.x;   // 819200 float4s
  int m = e4 >> 6, h4 = e4 & 63;
  int b = m / S_;
  int id = (int)idxf[m];
  float4 v = *(const float4*)&capv[((b*A_) + id)*H_ + 4*h4];
  *(float4*)&act[(size_t)4*e4] = v;
}

extern "C" void kernel_launch(void* const* d_in, const int* in_sizes, int n_in,
                              void* d_out, int out_size, void* d_ws, size_t ws_size,
                              hipStream_t stream) {
  (void)in_sizes; (void)n_in; (void)out_size; (void)ws_size;
  const float* item  = (const float*)d_in[0];
  const int*   iseq  = (const int*)d_in[1];
  const int*   tseq  = (const int*)d_in[2];
  const float* W_lin = (const float*)d_in[3];
  const float* b_lin = (const float*)d_in[4];
  const float* asp   = (const float*)d_in[5];
  const float* pos   = (const float*)d_in[6];
  const float* tdt   = (const float*)d_in[7];
  const float* tdn   = (const float*)d_in[8];
  const float* Wa1   = (const float*)d_in[9];
  const float* ba1   = (const float*)d_in[10];
  const float* Wa2   = (const float*)d_in[11];
  const float* ba2   = (const float*)d_in[12];
  const float* g_ln  = (const float*)d_in[13];
  const float* b_ln  = (const float*)d_in[14];

  float* out    = (float*)d_out;
  float* cap_o  = out;                 // B*A*H     = 262144
  float* gate_o = out + 262144;        // B*S*A     = 204800
  float* mask_o = out + 466944;        // B*A       = 1024
  float* act_o  = out + 467968;        // B*S*H     = 3276800 (moe scratch, then activated)
  float* aidx_o = out + 3744768;       // B*A       = 1024
  float* idx_o  = out + 3745792;       // B*S       = 12800
  float* w_ws   = (float*)d_ws;        // B*S floats

  phaseA_kernel<<<M_/TSA, 256, 0, stream>>>(item, iseq, tseq, W_lin, b_lin, asp,
      pos, tdt, tdn, Wa1, ba1, Wa2, ba2, g_ln, b_ln,
      gate_o, act_o, idx_o, w_ws);
  phaseC_kernel<<<B_, 1024, 0, stream>>>(iseq, w_ws, act_o, idx_o,
      gate_o, cap_o, mask_o, aidx_o);
  gather_kernel<<<(M_*H_/4)/256, 256, 0, stream>>>(cap_o, idx_o, act_o);
}